// Round 15
// baseline (319.196 us; speedup 1.0000x reference)
//
#include <hip/hip_runtime.h>
#include <cmath>

// Problem: x(128,64,32,128) f32; qkv_w(384,128); qkv_b(384); proj_w(128,128);
// proj_b(128); bias_table(225,4). H=4, D=1024 (merged N*C/H), scale=32^-0.5.
// qkv elem (b,s,t,h,d): rem=t*4096+h*1024+d; n=rem/384; j=rem%384 (128-chunks never straddle n).
// attn out (b,s,h,d) -> proj row = s*32+h*8+(d>>7), col = d&127.
// Per-batch strides: x = 262144 floats; out = 262144 floats.
// R15: R8 structure re-tiled to 16 waves/block (1024 thr) -> 32 waves/CU at same LDS.

typedef short bf16x8 __attribute__((ext_vector_type(8)));
typedef float f32x4  __attribute__((ext_vector_type(4)));
#define MFMA16 __builtin_amdgcn_mfma_f32_16x16x32_bf16

__device__ __forceinline__ unsigned rne16(float f) {
    unsigned u = __float_as_uint(f);
    return (u + 0x7fffu + ((u >> 16) & 1u)) & 0xffff0000u;   // bf16 RNE, kept in high bits
}
__device__ __forceinline__ void cvt8(float4 a, float4 b, bf16x8& H, bf16x8& L) {
    float f[8] = {a.x, a.y, a.z, a.w, b.x, b.y, b.z, b.w};
    #pragma unroll
    for (int i = 0; i < 8; ++i) {
        unsigned r = rne16(f[i]);
        H[i] = (short)(r >> 16);
        float fh = __uint_as_float(r);
        L[i] = (short)(rne16(f[i] - fh) >> 16);
    }
}
__device__ __forceinline__ void cvt8h(float4 a, float4 b, bf16x8& H) {
    float f[8] = {a.x, a.y, a.z, a.w, b.x, b.y, b.z, b.w};
    #pragma unroll
    for (int i = 0; i < 8; ++i) H[i] = (short)(rne16(f[i]) >> 16);
}

// ---------------- pre-kernels: split weights into hi/lo bf16, B-frag layouts ----------------
__global__ void split_w(const float* __restrict__ qw, unsigned short* __restrict__ wsp) {
    int idx = blockIdx.x * 256 + threadIdx.x;          // 0..49151
    if (idx >= 49152) return;
    int j = idx >> 7, c = idx & 127;
    float v = qw[idx];
    unsigned r = rne16(v);
    unsigned rl = rne16(v - __uint_as_float(r));
    int dest = (((j >> 5) * 16 + (c >> 3)) * 32 + (j & 31)) * 8 + (c & 7);
    wsp[dest] = (unsigned short)(r >> 16);
    wsp[49152 + dest] = (unsigned short)(rl >> 16);
}
__global__ void split_pw(const float* __restrict__ pw, unsigned short* __restrict__ pwsp) {
    int idx = blockIdx.x * 256 + threadIdx.x;          // 0..16383
    if (idx >= 16384) return;
    int cp = idx >> 7, c = idx & 127;
    float v = pw[idx];
    unsigned r = rne16(v);
    unsigned rl = rne16(v - __uint_as_float(r));
    int dest = ((c >> 3) * 128 + cp) * 8 + (c & 7);
    pwsp[dest] = (unsigned short)(r >> 16);
    pwsp[16384 + dest] = (unsigned short)(rl >> 16);
}

// ---------------- Kernel A16: R8 layout, 16 waves/block ----------------
// wave w (0..15): qt=w&3 (16-row tile), cq=w>>2 (32-col quarter / 16-t quarter)
// LDS: QC0 0, KC0 16640, QC1 33280, KC1 49920   ([d>>3 16x1040][s 64][d&7] bf16)
//      P 66560..74880 ([t>>3 8x1040][s][t&7] bf16)
//      SMA 74880 [4][64] f32 ; SMB 75904 [4][64] f32 ; total 76928
//      VC0 overlays QC0, VC1 overlays KC0  ([t>>3 8x2080][d 128][t&7])
constexpr int A16_QC0 = 0,     A16_KC0 = 16640;
constexpr int A16_QC1 = 33280, A16_KC1 = 49920;
constexpr int A16_P   = 66560;
constexpr int A16_SMA = 74880;
constexpr int A16_SMB = 75904;
constexpr int A16_VC0 = 0,     A16_VC1 = 16640;
constexpr int A16_LDS = 76928;

__global__ __launch_bounds__(1024, 8)
void attn_mfma16(const float* __restrict__ x,
                 const float* __restrict__ qkv_b,
                 const float* __restrict__ bias_table,
                 const unsigned short* __restrict__ wsp,
                 float* __restrict__ out)
{
    __shared__ __attribute__((aligned(128))) char lds[A16_LDS];
    const int tid = threadIdx.x;
    const int lane = tid & 63;
    const int w = tid >> 6;                // 0..15
    const int l15 = lane & 15, lg = lane >> 4;
    const int qt = w & 3, cq = w >> 2;     // row tile / col-quarter (or t-quarter)
    const int rowbase = qt * 16;
    const int b = blockIdx.x >> 2, h = blockIdx.x & 3;
    const float* __restrict__ xb = x + (size_t)b * 262144;
    const float* xrow0 = xb + (size_t)(rowbase + l15) * 4096 + lg * 8;

    bf16x8 aH[4];           // q-side / v-side x-frag cache
    bf16x8 kH[4];           // k-side x-frag cache
    int cur_na = -1, cur_nk = -1;

    auto loadfrags = [&](int n0, bf16x8 (&H)[4]) {
        const float* p = xrow0 + (size_t)n0 * 128;
        #pragma unroll
        for (int ks = 0; ks < 4; ++ks) {
            float4 a = *(const float4*)(p + ks * 32);
            float4 c = *(const float4*)(p + ks * 32 + 4);
            cvt8h(a, c, H[ks]);
        }
    };

    // production: rows = own 16, cols = wave's 32-quarter of [j0..j0+127], K=128
    auto prod32 = [&](const bf16x8 (&H)[4], int j0, f32x4 (&acc)[2]) {
        const unsigned short* wb = wsp + (size_t)(j0 >> 5) * 4096 + (size_t)cq * 4096;
        #pragma unroll
        for (int ks = 0; ks < 4; ++ks) {
            const int rb_ = ((ks * 4 + lg) * 32 + l15) * 8;
            bf16x8 b0 = *(const bf16x8*)(wb + rb_);
            bf16x8 b1 = *(const bf16x8*)(wb + rb_ + 128);
            acc[0] = MFMA16(H[ks], b0, acc[0], 0, 0, 0);
            acc[1] = MFMA16(H[ks], b1, acc[1], 0, 0, 0);
        }
    };

    // store production tile (+bias) as bf16 into [d>>3][s][d&7]
    auto storeP32 = [&](int base, f32x4 (&acc)[2], int j0) {
        #pragma unroll
        for (int ct = 0; ct < 2; ++ct) {
            int d = (cq * 2 + ct) * 16 + l15;
            float bias = qkv_b[j0 + d];
            int dofs = (d >> 3) * 1040 + (d & 7) * 2;
            #pragma unroll
            for (int reg = 0; reg < 4; ++reg) {
                int s = rowbase + lg * 4 + reg;
                *(unsigned short*)(lds + base + dofs + s * 16) =
                    (unsigned short)(rne16(acc[ct][reg] + bias) >> 16);
            }
        }
    };

    auto prodQK = [&](int cc) {
        int remq = h * 1024 + 128 * cc;
        int nq = remq / 384, j0q = remq - nq * 384;
        int remk = 4096 + h * 1024 + 128 * cc;
        int nk = remk / 384, j0k = remk - nk * 384;
        if (nq != cur_na) { loadfrags(nq, aH); cur_na = nq; }
        if (nk != cur_nk) { loadfrags(nk, kH); cur_nk = nk; }
        f32x4 qa[2];
        qa[0] = (f32x4){0.f, 0.f, 0.f, 0.f};
        qa[1] = (f32x4){0.f, 0.f, 0.f, 0.f};
        prod32(aH, j0q, qa);
        storeP32((cc & 1) ? A16_QC1 : A16_QC0, qa, j0q);
        f32x4 ka[2];
        ka[0] = (f32x4){0.f, 0.f, 0.f, 0.f};
        ka[1] = (f32x4){0.f, 0.f, 0.f, 0.f};
        prod32(kH, j0k, ka);
        storeP32((cc & 1) ? A16_KC1 : A16_KC0, ka, j0k);
    };

    // ---------------- QK^T phase: produce-ahead pipeline ----------------
    f32x4 accQK = (f32x4){0.f, 0.f, 0.f, 0.f};

    prodQK(0);
    __syncthreads();          // tile 0 ready

    for (int cc = 0; cc < 8; ++cc) {
        if (cc < 7) prodQK(cc + 1);   // produce next (other buffer)

        int qcb = (cc & 1) ? A16_QC1 : A16_QC0;
        int kcb = (cc & 1) ? A16_KC1 : A16_KC0;
        #pragma unroll
        for (int kst = 0; kst < 4; ++kst) {
            int grp = (kst * 4 + lg) * 1040;
            bf16x8 qh = *(const bf16x8*)(lds + qcb + grp + (rowbase + l15) * 16);
            bf16x8 kh = *(const bf16x8*)(lds + kcb + grp + (cq * 16 + l15) * 16);
            accQK = MFMA16(qh, kh, accQK, 0, 0, 0);
        }
        __syncthreads();      // store(cc+1) complete; reads(cc) complete
    }

    // ---------------- softmax: rows s = rowbase+lg*4+reg; wave holds t-quarter cq ----------------
    {
        const float scale = 0.17677669529663687f;
        float* smA = (float*)(lds + A16_SMA);
        float* smB = (float*)(lds + A16_SMB);
        float ex[4];
        #pragma unroll
        for (int reg = 0; reg < 4; ++reg) {
            int s = rowbase + lg * 4 + reg;
            int i1 = s >> 3, j1 = s & 7;
            int t = cq * 16 + l15;
            int i2 = t >> 3, j2 = t & 7;
            float L = accQK[reg] * scale
                    + bias_table[((i1 - i2 + 7) * 15 + (j1 - j2 + 7)) * 4 + h];
            ex[reg] = L;
            float m = L;
            m = fmaxf(m, __shfl_xor(m, 1));
            m = fmaxf(m, __shfl_xor(m, 2));
            m = fmaxf(m, __shfl_xor(m, 4));
            m = fmaxf(m, __shfl_xor(m, 8));
            if (l15 == 0) smA[cq * 64 + s] = m;
        }
        __syncthreads();
        #pragma unroll
        for (int reg = 0; reg < 4; ++reg) {
            int s = rowbase + lg * 4 + reg;
            float mg = fmaxf(fmaxf(smA[s], smA[64 + s]), fmaxf(smA[128 + s], smA[192 + s]));
            float e = __expf(ex[reg] - mg);
            ex[reg] = e;
            float sum = e;
            sum += __shfl_xor(sum, 1);
            sum += __shfl_xor(sum, 2);
            sum += __shfl_xor(sum, 4);
            sum += __shfl_xor(sum, 8);
            if (l15 == 0) smB[cq * 64 + s] = sum;
        }
        __syncthreads();
        #pragma unroll
        for (int reg = 0; reg < 4; ++reg) {
            int s = rowbase + lg * 4 + reg;
            float inv = 1.f / (smB[s] + smB[64 + s] + smB[128 + s] + smB[192 + s]);
            int t = cq * 16 + l15;
            int off = (t >> 3) * 1040 + s * 16 + (t & 7) * 2;
            *(unsigned short*)(lds + A16_P + off) =
                (unsigned short)(rne16(ex[reg] * inv) >> 16);
        }
    }
    // VC0/VC1 overlay QC0/KC0: last QK reads were >=2 barriers before first PV write.

    // ---------------- PV phase: produce-ahead pipeline ----------------
    cur_na = -1;
    float* ob = out + (size_t)b * 262144;

    auto prodV = [&](int cc) {
        int remv = 8192 + h * 1024 + 128 * cc;
        int nv = remv / 384, j0v = remv - nv * 384;
        if (nv != cur_na) { loadfrags(nv, aH); cur_na = nv; }
        f32x4 va[2];
        va[0] = (f32x4){0.f, 0.f, 0.f, 0.f};
        va[1] = (f32x4){0.f, 0.f, 0.f, 0.f};
        prod32(aH, j0v, va);
        int vcb = (cc & 1) ? A16_VC1 : A16_VC0;
        #pragma unroll
        for (int ct = 0; ct < 2; ++ct) {
            int d = (cq * 2 + ct) * 16 + l15;
            float bias = qkv_b[j0v + d];
            #pragma unroll
            for (int reg = 0; reg < 4; ++reg) {
                int t = rowbase + lg * 4 + reg;
                int off = (t >> 3) * 2080 + d * 16 + (t & 7) * 2;
                *(unsigned short*)(lds + vcb + off) =
                    (unsigned short)(rne16(va[ct][reg] + bias) >> 16);
            }
        }
    };

    prodV(0);                 // writes VC0 (overlays QC0)
    __syncthreads();          // VC0 + P visible

    for (int cc = 0; cc < 8; ++cc) {
        if (cc < 7) prodV(cc + 1);

        int vcb = (cc & 1) ? A16_VC1 : A16_VC0;
        f32x4 o[2];
        o[0] = (f32x4){0.f, 0.f, 0.f, 0.f};
        o[1] = (f32x4){0.f, 0.f, 0.f, 0.f};
        #pragma unroll
        for (int kst = 0; kst < 2; ++kst) {
            bf16x8 pf = *(const bf16x8*)(lds + A16_P + (kst * 4 + lg) * 1040 + (rowbase + l15) * 16);
            int vgrp = (kst * 4 + lg) * 2080;
            #pragma unroll
            for (int dt = 0; dt < 2; ++dt) {
                int drow = ((cq * 2 + dt) * 16 + l15) * 16;
                bf16x8 vh = *(const bf16x8*)(lds + vcb + vgrp + drow);
                o[dt] = MFMA16(pf, vh, o[dt], 0, 0, 0);
            }
        }

        #pragma unroll
        for (int reg = 0; reg < 4; ++reg) {
            int s = rowbase + lg * 4 + reg;
            float* orow = ob + (size_t)(s * 32 + h * 8 + cc) * 128;
            #pragma unroll
            for (int dt = 0; dt < 2; ++dt)
                orow[(cq * 2 + dt) * 16 + l15] = o[dt][reg];
        }
        __syncthreads();
    }
}

// ---------------- Kernel B2: proj via MFMA, register-only (at HBM roofline) ----------------
__global__ __launch_bounds__(256, 4)
void proj_mfma(const unsigned short* __restrict__ pwsp,
               const float* __restrict__ pb,
               float* __restrict__ io)
{
    const int tid = threadIdx.x;
    const int lane = tid & 63;
    const int w = tid >> 6;
    const int l15 = lane & 15, lg = lane >> 4;
    const size_t rbase = (size_t)blockIdx.x * 64 + w * 16;

    const float* rp = io + (rbase + l15) * 128 + lg * 8;
    bf16x8 aH[4], aL[4];
    #pragma unroll
    for (int ks = 0; ks < 4; ++ks) {
        float4 a = *(const float4*)(rp + ks * 32);
        float4 c = *(const float4*)(rp + ks * 32 + 4);
        cvt8(a, c, aH[ks], aL[ks]);
    }

    f32x4 acc[8];
    #pragma unroll
    for (int i = 0; i < 8; ++i) acc[i] = (f32x4){0.f, 0.f, 0.f, 0.f};

    #pragma unroll
    for (int ks = 0; ks < 4; ++ks) {
        #pragma unroll
        for (int ct = 0; ct < 8; ++ct) {
            int ro = ((ks * 4 + lg) * 128 + ct * 16 + l15) * 8;
            bf16x8 bh = *(const bf16x8*)(pwsp + ro);
            bf16x8 bl = *(const bf16x8*)(pwsp + 16384 + ro);
            acc[ct] = MFMA16(aH[ks], bh, acc[ct], 0, 0, 0);
            acc[ct] = MFMA16(aH[ks], bl, acc[ct], 0, 0, 0);
            acc[ct] = MFMA16(aL[ks], bh, acc[ct], 0, 0, 0);
        }
    }

    #pragma unroll
    for (int ct = 0; ct < 8; ++ct) {
        float bias = pb[ct * 16 + l15];
        #pragma unroll
        for (int reg = 0; reg < 4; ++reg)
            io[(rbase + lg * 4 + reg) * 128 + ct * 16 + l15] = acc[ct][reg] + bias;
    }
}

// ---------------- round-4 fallback kernels (known-correct) ----------------
constexpr int QC_OFF = 0;
constexpr int KC_OFF = 8320;
constexpr int VC_OFF = 24960;
constexpr int P_OFF  = 41856;
constexpr int LDS_TOT = 50176;

__global__ __launch_bounds__(256, 2)
void attn_mfma(const float* __restrict__ x,
               const float* __restrict__ qkv_b,
               const float* __restrict__ bias_table,
               const unsigned short* __restrict__ wsp,
               float* __restrict__ out)
{
    __shared__ __attribute__((aligned(128))) char lds[LDS_TOT];
    const int tid = threadIdx.x;
    const int lane = tid & 63;
    const int w = tid >> 6;
    const int l15 = lane & 15, lg = lane >> 4;
    const int rowbase = 16 * w;
    const int b = blockIdx.x >> 2, h = blockIdx.x & 3;
    const float* __restrict__ xb = x + (size_t)b * 262144;
    const float* xrow0 = xb + ((size_t)(rowbase + l15) * 32) * 128 + lg * 8;

    bf16x8 aH[4], aL[4];
    bf16x8 kH[4], kL[4];
    int cur_na = -1, cur_nk = -1;

    auto loadfrags = [&](int n0, bf16x8 (&H)[4], bf16x8 (&L)[4]) {
        const float* p = xrow0 + (size_t)n0 * 128;
        #pragma unroll
        for (int ks = 0; ks < 4; ++ks) {
            float4 a = *(const float4*)(p + ks * 32);
            float4 c = *(const float4*)(p + ks * 32 + 4);
            cvt8(a, c, H[ks], L[ks]);
        }
    };

    auto mm_band = [&](const bf16x8 (&H)[4], const bf16x8 (&L)[4], int band,
                       f32x4& a0, f32x4& a1) {
        const unsigned short* wb = wsp + (size_t)band * 4096;
        #pragma unroll
        for (int ks = 0; ks < 4; ++ks) {
            int ro = ((ks * 4 + lg) * 32 + l15) * 8;
            bf16x8 b0h = *(const bf16x8*)(wb + ro);
            bf16x8 b0l = *(const bf16x8*)(wb + 49152 + ro);
            bf16x8 b1h = *(const bf16x8*)(wb + ro + 128);
            bf16x8 b1l = *(const bf16x8*)(wb + 49152 + ro + 128);
            a0 = MFMA16(H[ks], b0h, a0, 0, 0, 0);
            a0 = MFMA16(H[ks], b0l, a0, 0, 0, 0);
            a0 = MFMA16(L[ks], b0h, a0, 0, 0, 0);
            a1 = MFMA16(H[ks], b1h, a1, 0, 0, 0);
            a1 = MFMA16(H[ks], b1l, a1, 0, 0, 0);
            a1 = MFMA16(L[ks], b1h, a1, 0, 0, 0);
        }
    };

    auto store_rc = [&](char* base, f32x4 a0, f32x4 a1, float b0, float b1) {
        #pragma unroll
        for (int reg = 0; reg < 4; ++reg) {
            int s = rowbase + lg * 4 + reg;
            {
                float v = a0[reg] + b0;
                int i = l15;
                int off = (i >> 3) * 1040 + s * 16 + (i & 7) * 2;
                unsigned r = rne16(v);
                *(unsigned short*)(base + off) = (unsigned short)(r >> 16);
                *(unsigned short*)(base + 4160 + off) =
                    (unsigned short)(rne16(v - __uint_as_float(r)) >> 16);
            }
            {
                float v = a1[reg] + b1;
                int i = 16 + l15;
                int off = (i >> 3) * 1040 + s * 16 + (i & 7) * 2;
                unsigned r = rne16(v);
                *(unsigned short*)(base + off) = (unsigned short)(r >> 16);
                *(unsigned short*)(base + 4160 + off) =
                    (unsigned short)(rne16(v - __uint_as_float(r)) >> 16);
            }
        }
    };

    f32x4 accQK[4];
    #pragma unroll
    for (int tt = 0; tt < 4; ++tt) accQK[tt] = (f32x4){0.f, 0.f, 0.f, 0.f};

    int buf = 0;
    for (int ccc = 0; ccc < 32; ++ccc) {
        int remq = h * 1024 + 32 * ccc;
        int nq = remq / 384, j0q = remq - nq * 384, bandq = j0q >> 5;
        int remk = 4096 + h * 1024 + 32 * ccc;
        int nk = remk / 384, j0k = remk - nk * 384, bandk = j0k >> 5;
        if (nq != cur_na) { loadfrags(nq, aH, aL); cur_na = nq; }
        if (nk != cur_nk) { loadfrags(nk, kH, kL); cur_nk = nk; }

        f32x4 q0 = (f32x4){0.f,0.f,0.f,0.f}, q1 = (f32x4){0.f,0.f,0.f,0.f};
        mm_band(aH, aL, bandq, q0, q1);
        store_rc(lds + QC_OFF, q0, q1, qkv_b[j0q + l15], qkv_b[j0q + 16 + l15]);

        f32x4 k0 = (f32x4){0.f,0.f,0.f,0.f}, k1 = (f32x4){0.f,0.f,0.f,0.f};
        mm_band(kH, kL, bandk, k0, k1);
        store_rc(lds + KC_OFF + buf * 8320, k0, k1, qkv_b[j0k + l15], qkv_b[j0k + 16 + l15]);

        __syncthreads();

        const char* qc = lds + QC_OFF + lg * 1040 + (rowbase + l15) * 16;
        bf16x8 qah = *(const bf16x8*)qc;
        bf16x8 qal = *(const bf16x8*)(qc + 4160);
        #pragma unroll
        for (int tt = 0; tt < 4; ++tt) {
            const char* kc = lds + KC_OFF + buf * 8320 + lg * 1040 + (tt * 16 + l15) * 16;
            bf16x8 kbh = *(const bf16x8*)kc;
            bf16x8 kbl = *(const bf16x8*)(kc + 4160);
            accQK[tt] = MFMA16(qah, kbh, accQK[tt], 0, 0, 0);
            accQK[tt] = MFMA16(qah, kbl, accQK[tt], 0, 0, 0);
            accQK[tt] = MFMA16(qal, kbh, accQK[tt], 0, 0, 0);
        }
        buf ^= 1;
    }

    {
        const float scale = 0.17677669529663687f;
        #pragma unroll
        for (int reg = 0; reg < 4; ++reg) {
            int s = rowbase + lg * 4 + reg;
            int i1 = s >> 3, j1 = s & 7;
            float Lv[4];
            float m = -1e30f;
            #pragma unroll
            for (int tt = 0; tt < 4; ++tt) {
                int t = tt * 16 + l15;
                int i2 = t >> 3, j2 = t & 7;
                float L = accQK[tt][reg] * scale
                        + bias_table[((i1 - i2 + 7) * 15 + (j1 - j2 + 7)) * 4 + h];
                Lv[tt] = L;
                m = fmaxf(m, L);
            }
            m = fmaxf(m, __shfl_xor(m, 1));
            m = fmaxf(m, __shfl_xor(m, 2));
            m = fmaxf(m, __shfl_xor(m, 4));
            m = fmaxf(m, __shfl_xor(m, 8));
            float sum = 0.f;
            #pragma unroll
            for (int tt = 0; tt < 4; ++tt) { Lv[tt] = __expf(Lv[tt] - m); sum += Lv[tt]; }
            sum += __shfl_xor(sum, 1);
            sum += __shfl_xor(sum, 2);
            sum += __shfl_xor(sum, 4);
            sum += __shfl_xor(sum, 8);
            float inv = 1.f / sum;
            #pragma unroll
            for (int tt = 0; tt < 4; ++tt) {
                int t = tt * 16 + l15;
                int off = (t >> 3) * 1040 + s * 16 + (t & 7) * 2;
                *(unsigned short*)(lds + P_OFF + off) = (unsigned short)(rne16(Lv[tt] * inv) >> 16);
            }
        }
    }

    cur_na = -1;
    int bufv = 0;
    float* ob = out + (size_t)b * 262144;
    for (int ccc = 0; ccc < 32; ++ccc) {
        int remv = 8192 + h * 1024 + 32 * ccc;
        int nv = remv / 384, j0v = remv - nv * 384, bandv = j0v >> 5;
        if (nv != cur_na) { loadfrags(nv, aH, aL); cur_na = nv; }

        f32x4 v0 = (f32x4){0.f,0.f,0.f,0.f}, v1 = (f32x4){0.f,0.f,0.f,0.f};
        mm_band(aH, aL, bandv, v0, v1);
        {
            char* base = lds + VC_OFF + bufv * 8448;
            float b0 = qkv_b[j0v + l15], b1 = qkv_b[j0v + 16 + l15];
            #pragma unroll
            for (int reg = 0; reg < 4; ++reg) {
                int t = rowbase + lg * 4 + reg;
                {
                    float v = v0[reg] + b0;
                    int i = l15;
                    int off = (t >> 3) * 528 + i * 16 + (t & 7) * 2;
                    unsigned r = rne16(v);
                    *(unsigned short*)(base + off) = (unsigned short)(r >> 16);
                    *(unsigned short*)(base + 4224 + off) =
                        (unsigned short)(rne16(v - __uint_as_float(r)) >> 16);
                }
                {
                    float v = v1[reg] + b1;
                    int i = 16 + l15;
                    int off = (t >> 3) * 528 + i * 16 + (t & 7) * 2;
                    unsigned r = rne16(v);
                    *(unsigned short*)(base + off) = (unsigned short)(r >> 16);
                    *(unsigned short*)(base + 4224 + off) =
                        (unsigned short)(rne16(v - __uint_as_float(r)) >> 16);
                }
            }
        }
        __syncthreads();

        f32x4 o0 = (f32x4){0.f,0.f,0.f,0.f}, o1 = (f32x4){0.f,0.f,0.f,0.f};
        #pragma unroll
        for (int ks = 0; ks < 2; ++ks) {
            bf16x8 pf = *(const bf16x8*)(lds + P_OFF + (ks * 4 + lg) * 1040 + (rowbase + l15) * 16);
            const char* vb = lds + VC_OFF + bufv * 8448 + (ks * 4 + lg) * 528;
            bf16x8 v0h = *(const bf16x8*)(vb + l15 * 16);
            bf16x8 v0l = *(const bf16x8*)(vb + 4224 + l15 * 16);
            bf16x8 v1h = *(const bf16x8*)(vb + (16 + l15) * 16);
            bf16x8 v1l = *(const bf16x8*)(vb + 4224 + (16 + l15) * 16);
            o0 = MFMA16(pf, v0h, o0, 0, 0, 0);
            o0 = MFMA16(pf, v0l, o0, 0, 0, 0);
            o1 = MFMA16(pf, v1h, o1, 0, 0, 0);
            o1 = MFMA16(pf, v1l, o1, 0, 0, 0);
        }
        bufv ^= 1;

        #pragma unroll
        for (int reg = 0; reg < 4; ++reg) {
            int s = rowbase + lg * 4 + reg;
            {
                int d = 32 * ccc + l15;
                ob[(s * 32 + h * 8 + (d >> 7)) * 128 + (d & 127)] = o0[reg];
            }
            {
                int d = 32 * ccc + 16 + l15;
                ob[(s * 32 + h * 8 + (d >> 7)) * 128 + (d & 127)] = o1[reg];
            }
        }
    }
}

constexpr int LDS_B = 128 * 132 + 64 * 132;

__global__ __launch_bounds__(256, 1)
void proj_inplace(const float* __restrict__ pw,
                  const float* __restrict__ pb,
                  float* __restrict__ io)
{
    __shared__ float lds[LDS_B];
    float* pwt  = lds;
    float* rows = lds + 128 * 132;
    const int tid = threadIdx.x;

    for (int idx = tid; idx < 128 * 128; idx += 256) {
        const int c = idx >> 7, cp = idx & 127;
        pwt[cp * 132 + c] = pw[idx];
    }
    const int rb = tid >> 5;
    const int cg = tid & 31;
    const float4 pbv = *(const float4*)(pb + cg * 4);

    for (int it = 0; it < 8; ++it) {
        const size_t base = ((size_t)blockIdx.x * 8 + it) * 64;
        __syncthreads();
        for (int f = tid; f < 64 * 32; f += 256) {
            const int r = f >> 5, c4 = f & 31;
            *(float4*)(rows + r * 132 + c4 * 4) =
                *(const float4*)(io + (base + r) * 128 + c4 * 4);
        }
        __syncthreads();
        float acc[8][4] = {};
        #pragma unroll 2
        for (int cp = 0; cp < 128; ++cp) {
            const float4 wv = *(const float4*)(pwt + cp * 132 + cg * 4);
            #pragma unroll
            for (int rr = 0; rr < 8; ++rr) {
                const float xv = rows[(rb * 8 + rr) * 132 + cp];
                acc[rr][0] += xv * wv.x;
                acc[rr][1] += xv * wv.y;
                acc[rr][2] += xv * wv.z;
                acc[rr][3] += xv * wv.w;
            }
        }
        #pragma unroll
        for (int rr = 0; rr < 8; ++rr) {
            float4 o;
            o.x = acc[rr][0] + pbv.x;
            o.y = acc[rr][1] + pbv.y;
            o.z = acc[rr][2] + pbv.z;
            o.w = acc[rr][3] + pbv.w;
            *(float4*)(io + (base + rb * 8 + rr) * 128 + cg * 4) = o;
        }
    }
}

extern "C" void kernel_launch(void* const* d_in, const int* in_sizes, int n_in,
                              void* d_out, int out_size, void* d_ws, size_t ws_size,
                              hipStream_t stream)
{
    const float* x          = (const float*)d_in[0];
    const float* qkv_w      = (const float*)d_in[1];
    const float* qkv_b      = (const float*)d_in[2];
    const float* proj_w     = (const float*)d_in[3];
    const float* proj_b     = (const float*)d_in[4];
    const float* bias_table = (const float*)d_in[5];
    float* out = (float*)d_out;

    if (ws_size >= 262144 && d_ws != nullptr) {
        unsigned short* wsp = (unsigned short*)d_ws;
        unsigned short* pwsp = wsp + 98304;
        split_w<<<dim3(192), dim3(256), 0, stream>>>(qkv_w, wsp);
        split_pw<<<dim3(64), dim3(256), 0, stream>>>(proj_w, pwsp);
        attn_mfma16<<<dim3(512), dim3(1024), 0, stream>>>(x, qkv_b, bias_table, wsp, out);
        proj_mfma<<<dim3(4096), dim3(256), 0, stream>>>(pwsp, proj_b, out);
    } else if (ws_size >= 196608 && d_ws != nullptr) {
        unsigned short* wsp = (unsigned short*)d_ws;
        split_w<<<dim3(192), dim3(256), 0, stream>>>(qkv_w, wsp);
        attn_mfma<<<dim3(512), dim3(256), 0, stream>>>(x, qkv_b, bias_table, wsp, out);
        proj_inplace<<<dim3(512), dim3(256), 0, stream>>>(proj_w, proj_b, out);
    }
}

// Round 16
// 191.872 us; speedup vs baseline: 1.6636x; 1.6636x over previous
//
#include <hip/hip_runtime.h>
#include <cmath>

// Problem: x(128,64,32,128) f32; qkv_w(384,128); qkv_b(384); proj_w(128,128);
// proj_b(128); bias_table(225,4). H=4, D=1024 (merged N*C/H), scale=32^-0.5.
// qkv elem (b,s,t,h,d): rem=t*4096+h*1024+d; n=rem/384; j=rem%384 (128-chunks never straddle n).
// attn out (b,s,h,d) -> proj row = s*32+h*8+(d>>7), col = d&127.
// Per-batch strides: x = 262144 floats; out = 262144 floats.
// FINAL best-validated config (R8/R14): attn ~142-148us + proj ~43us, absmax 2.44e-4.
// R9-R15 falsified: setprio/burst (spill), proj fusion (spill), single-buffer diet /
// 64-chunk / s-split / 16-wave retile (occupancy gains never convert: reg budget or
// duplicated work dominates). Remaining gap is latency-structural (producer/consumer
// wave specialization with counted vmcnt in asm), out of scope for HIP-source rounds.

typedef short bf16x8 __attribute__((ext_vector_type(8)));
typedef float f32x4  __attribute__((ext_vector_type(4)));
#define MFMA16 __builtin_amdgcn_mfma_f32_16x16x32_bf16

__device__ __forceinline__ unsigned rne16(float f) {
    unsigned u = __float_as_uint(f);
    return (u + 0x7fffu + ((u >> 16) & 1u)) & 0xffff0000u;   // bf16 RNE, kept in high bits
}
__device__ __forceinline__ void cvt8(float4 a, float4 b, bf16x8& H, bf16x8& L) {
    float f[8] = {a.x, a.y, a.z, a.w, b.x, b.y, b.z, b.w};
    #pragma unroll
    for (int i = 0; i < 8; ++i) {
        unsigned r = rne16(f[i]);
        H[i] = (short)(r >> 16);
        float fh = __uint_as_float(r);
        L[i] = (short)(rne16(f[i] - fh) >> 16);
    }
}
__device__ __forceinline__ void cvt8h(float4 a, float4 b, bf16x8& H) {
    float f[8] = {a.x, a.y, a.z, a.w, b.x, b.y, b.z, b.w};
    #pragma unroll
    for (int i = 0; i < 8; ++i) H[i] = (short)(rne16(f[i]) >> 16);
}

// ---------------- pre-kernels: split weights into hi/lo bf16, B-frag layouts ----------------
__global__ void split_w(const float* __restrict__ qw, unsigned short* __restrict__ wsp) {
    int idx = blockIdx.x * 256 + threadIdx.x;          // 0..49151
    if (idx >= 49152) return;
    int j = idx >> 7, c = idx & 127;
    float v = qw[idx];
    unsigned r = rne16(v);
    unsigned rl = rne16(v - __uint_as_float(r));
    int dest = (((j >> 5) * 16 + (c >> 3)) * 32 + (j & 31)) * 8 + (c & 7);
    wsp[dest] = (unsigned short)(r >> 16);
    wsp[49152 + dest] = (unsigned short)(rl >> 16);
}
__global__ void split_pw(const float* __restrict__ pw, unsigned short* __restrict__ pwsp) {
    int idx = blockIdx.x * 256 + threadIdx.x;          // 0..16383
    if (idx >= 16384) return;
    int cp = idx >> 7, c = idx & 127;
    float v = pw[idx];
    unsigned r = rne16(v);
    unsigned rl = rne16(v - __uint_as_float(r));
    int dest = ((c >> 3) * 128 + cp) * 8 + (c & 7);
    pwsp[dest] = (unsigned short)(r >> 16);
    pwsp[16384 + dest] = (unsigned short)(rl >> 16);
}

// ---------------- Kernel A5b: R8 structure (produce-ahead dbuf, 8 waves) ----------------
// wave w: qt=w&3 (16-row tile), ch=w>>2 (64-col half)
// LDS: QC0 0, KC0 16640, QC1 33280, KC1 49920   ([d>>3 16x1040][s 64][d&7] bf16)
//      P 66560..74880 ([t>>3 8x1040][s][t&7] bf16) ; SMA 74880 [2][64] f32 ; SMB 75392
//      VC0 overlays QC0, VC1 overlays KC0  ([t>>3 8x2080][d 128][t&7])
constexpr int A5_QC0 = 0,     A5_KC0 = 16640;
constexpr int A5_QC1 = 33280, A5_KC1 = 49920;
constexpr int A5_P   = 66560;
constexpr int A5_SMA = 74880;
constexpr int A5_SMB = 75392;
constexpr int A5_VC0 = 0,     A5_VC1 = 16640;
constexpr int A5_LDS = 75904;

__global__ __launch_bounds__(512, 4)
void attn_mfma5b(const float* __restrict__ x,
                 const float* __restrict__ qkv_b,
                 const float* __restrict__ bias_table,
                 const unsigned short* __restrict__ wsp,
                 float* __restrict__ out)
{
    __shared__ __attribute__((aligned(128))) char lds[A5_LDS];
    const int tid = threadIdx.x;
    const int lane = tid & 63;
    const int w = tid >> 6;
    const int l15 = lane & 15, lg = lane >> 4;
    const int qt = w & 3, ch = w >> 2;
    const int rowbase = qt * 16;
    const int b = blockIdx.x >> 2, h = blockIdx.x & 3;
    const float* __restrict__ xb = x + (size_t)b * 262144;
    const float* xrow0 = xb + (size_t)(rowbase + l15) * 4096 + lg * 8;

    bf16x8 aH[4];           // q-side / v-side x-frag cache
    bf16x8 kH[4];           // k-side x-frag cache
    int cur_na = -1, cur_nk = -1;

    auto loadfrags = [&](int n0, bf16x8 (&H)[4]) {
        const float* p = xrow0 + (size_t)n0 * 128;
        #pragma unroll
        for (int ks = 0; ks < 4; ++ks) {
            float4 a = *(const float4*)(p + ks * 32);
            float4 c = *(const float4*)(p + ks * 32 + 4);
            cvt8h(a, c, H[ks]);
        }
    };

    // production: rows = own 16, cols = wave's 64-half of [j0..j0+127], K=128.
    auto prod64 = [&](const bf16x8 (&H)[4], int j0, f32x4 (&acc)[4]) {
        const unsigned short* wb = wsp + (size_t)(j0 >> 5) * 4096;
        #pragma unroll
        for (int ks = 0; ks < 4; ++ks) {
            const int rb_ = (ks * 4 + lg) * 32 + l15;
            bf16x8 b0 = *(const bf16x8*)(wb + (size_t)(ch * 2 + 0) * 4096 + (rb_ +  0) * 8);
            bf16x8 b1 = *(const bf16x8*)(wb + (size_t)(ch * 2 + 0) * 4096 + (rb_ + 16) * 8);
            bf16x8 b2 = *(const bf16x8*)(wb + (size_t)(ch * 2 + 1) * 4096 + (rb_ +  0) * 8);
            bf16x8 b3 = *(const bf16x8*)(wb + (size_t)(ch * 2 + 1) * 4096 + (rb_ + 16) * 8);
            acc[0] = MFMA16(H[ks], b0, acc[0], 0, 0, 0);
            acc[1] = MFMA16(H[ks], b1, acc[1], 0, 0, 0);
            acc[2] = MFMA16(H[ks], b2, acc[2], 0, 0, 0);
            acc[3] = MFMA16(H[ks], b3, acc[3], 0, 0, 0);
        }
    };

    // store production tile (+bias) as bf16 into [d>>3][s][d&7]
    auto storeP64 = [&](int base, f32x4 (&acc)[4], int j0) {
        #pragma unroll
        for (int ct = 0; ct < 4; ++ct) {
            int d = (ch * 4 + ct) * 16 + l15;
            float bias = qkv_b[j0 + d];
            int dofs = (d >> 3) * 1040 + (d & 7) * 2;
            #pragma unroll
            for (int reg = 0; reg < 4; ++reg) {
                int s = rowbase + lg * 4 + reg;
                *(unsigned short*)(lds + base + dofs + s * 16) =
                    (unsigned short)(rne16(acc[ct][reg] + bias) >> 16);
            }
        }
    };

    auto prodQK = [&](int cc) {
        int remq = h * 1024 + 128 * cc;
        int nq = remq / 384, j0q = remq - nq * 384;
        int remk = 4096 + h * 1024 + 128 * cc;
        int nk = remk / 384, j0k = remk - nk * 384;
        if (nq != cur_na) { loadfrags(nq, aH); cur_na = nq; }
        if (nk != cur_nk) { loadfrags(nk, kH); cur_nk = nk; }
        f32x4 qa[4];
        #pragma unroll
        for (int i = 0; i < 4; ++i) qa[i] = (f32x4){0.f, 0.f, 0.f, 0.f};
        prod64(aH, j0q, qa);
        storeP64((cc & 1) ? A5_QC1 : A5_QC0, qa, j0q);
        f32x4 ka[4];
        #pragma unroll
        for (int i = 0; i < 4; ++i) ka[i] = (f32x4){0.f, 0.f, 0.f, 0.f};
        prod64(kH, j0k, ka);
        storeP64((cc & 1) ? A5_KC1 : A5_KC0, ka, j0k);
    };

    // ---------------- QK^T phase: produce-ahead pipeline ----------------
    f32x4 accQK[2];
    #pragma unroll
    for (int tt = 0; tt < 2; ++tt) accQK[tt] = (f32x4){0.f, 0.f, 0.f, 0.f};

    prodQK(0);
    __syncthreads();          // tile 0 ready

    for (int cc = 0; cc < 8; ++cc) {
        if (cc < 7) prodQK(cc + 1);   // produce next (independent of consume below)

        int qcb = (cc & 1) ? A5_QC1 : A5_QC0;
        int kcb = (cc & 1) ? A5_KC1 : A5_KC0;
        #pragma unroll
        for (int kst = 0; kst < 4; ++kst) {
            int grp = (kst * 4 + lg) * 1040;
            bf16x8 qh = *(const bf16x8*)(lds + qcb + grp + (rowbase + l15) * 16);
            #pragma unroll
            for (int tt = 0; tt < 2; ++tt) {
                int trow = ((ch * 2 + tt) * 16 + l15) * 16;
                bf16x8 kh = *(const bf16x8*)(lds + kcb + grp + trow);
                accQK[tt] = MFMA16(qh, kh, accQK[tt], 0, 0, 0);
            }
        }
        __syncthreads();      // store(cc+1) complete; reads(cc) complete
    }

    // ---------------- softmax: rows s = rowbase+lg*4+reg, wave holds t-half (32) ----------------
    {
        const float scale = 0.17677669529663687f;
        float* smA = (float*)(lds + A5_SMA);
        float* smB = (float*)(lds + A5_SMB);
        float ex[4][2];
        #pragma unroll
        for (int reg = 0; reg < 4; ++reg) {
            int s = rowbase + lg * 4 + reg;
            int i1 = s >> 3, j1 = s & 7;
            float m = -1e30f;
            #pragma unroll
            for (int tt = 0; tt < 2; ++tt) {
                int t = (ch * 2 + tt) * 16 + l15;
                int i2 = t >> 3, j2 = t & 7;
                float L = accQK[tt][reg] * scale
                        + bias_table[((i1 - i2 + 7) * 15 + (j1 - j2 + 7)) * 4 + h];
                ex[reg][tt] = L;
                m = fmaxf(m, L);
            }
            m = fmaxf(m, __shfl_xor(m, 1));
            m = fmaxf(m, __shfl_xor(m, 2));
            m = fmaxf(m, __shfl_xor(m, 4));
            m = fmaxf(m, __shfl_xor(m, 8));
            if (l15 == 0) smA[ch * 64 + s] = m;
        }
        __syncthreads();
        #pragma unroll
        for (int reg = 0; reg < 4; ++reg) {
            int s = rowbase + lg * 4 + reg;
            float mg = fmaxf(smA[s], smA[64 + s]);
            float e0 = __expf(ex[reg][0] - mg);
            float e1 = __expf(ex[reg][1] - mg);
            ex[reg][0] = e0; ex[reg][1] = e1;
            float sum = e0 + e1;
            sum += __shfl_xor(sum, 1);
            sum += __shfl_xor(sum, 2);
            sum += __shfl_xor(sum, 4);
            sum += __shfl_xor(sum, 8);
            if (l15 == 0) smB[ch * 64 + s] = sum;
        }
        __syncthreads();
        #pragma unroll
        for (int reg = 0; reg < 4; ++reg) {
            int s = rowbase + lg * 4 + reg;
            float inv = 1.f / (smB[s] + smB[64 + s]);
            #pragma unroll
            for (int tt = 0; tt < 2; ++tt) {
                int t = (ch * 2 + tt) * 16 + l15;
                int off = (t >> 3) * 1040 + s * 16 + (t & 7) * 2;
                *(unsigned short*)(lds + A5_P + off) =
                    (unsigned short)(rne16(ex[reg][tt] * inv) >> 16);
            }
        }
    }

    // ---------------- PV phase: produce-ahead pipeline ----------------
    cur_na = -1;
    float* ob = out + (size_t)b * 262144;

    auto prodV = [&](int cc) {
        int remv = 8192 + h * 1024 + 128 * cc;
        int nv = remv / 384, j0v = remv - nv * 384;
        if (nv != cur_na) { loadfrags(nv, aH); cur_na = nv; }
        f32x4 va[4];
        #pragma unroll
        for (int i = 0; i < 4; ++i) va[i] = (f32x4){0.f, 0.f, 0.f, 0.f};
        prod64(aH, j0v, va);
        int vcb = (cc & 1) ? A5_VC1 : A5_VC0;
        #pragma unroll
        for (int ct = 0; ct < 4; ++ct) {
            int d = (ch * 4 + ct) * 16 + l15;
            float bias = qkv_b[j0v + d];
            #pragma unroll
            for (int reg = 0; reg < 4; ++reg) {
                int t = rowbase + lg * 4 + reg;
                int off = (t >> 3) * 2080 + d * 16 + (t & 7) * 2;
                *(unsigned short*)(lds + vcb + off) =
                    (unsigned short)(rne16(va[ct][reg] + bias) >> 16);
            }
        }
    };

    prodV(0);                 // writes VC0 (overlays QC0: last read >=3 barriers ago)
    __syncthreads();          // VC0 + P visible

    for (int cc = 0; cc < 8; ++cc) {
        if (cc < 7) prodV(cc + 1);

        int vcb = (cc & 1) ? A5_VC1 : A5_VC0;
        f32x4 o[4];
        #pragma unroll
        for (int i = 0; i < 4; ++i) o[i] = (f32x4){0.f, 0.f, 0.f, 0.f};
        #pragma unroll
        for (int kst = 0; kst < 2; ++kst) {
            bf16x8 pf = *(const bf16x8*)(lds + A5_P + (kst * 4 + lg) * 1040 + (rowbase + l15) * 16);
            int vgrp = (kst * 4 + lg) * 2080;
            #pragma unroll
            for (int dt = 0; dt < 4; ++dt) {
                int drow = ((ch * 4 + dt) * 16 + l15) * 16;
                bf16x8 vh = *(const bf16x8*)(lds + vcb + vgrp + drow);
                o[dt] = MFMA16(pf, vh, o[dt], 0, 0, 0);
            }
        }

        #pragma unroll
        for (int reg = 0; reg < 4; ++reg) {
            int s = rowbase + lg * 4 + reg;
            float* orow = ob + (size_t)(s * 32 + h * 8 + cc) * 128;
            #pragma unroll
            for (int dt = 0; dt < 4; ++dt)
                orow[(ch * 4 + dt) * 16 + l15] = o[dt][reg];
        }
        __syncthreads();
    }
}

// ---------------- Kernel B2: proj via MFMA, register-only (at HBM roofline) ----------------
__global__ __launch_bounds__(256, 4)
void proj_mfma(const unsigned short* __restrict__ pwsp,
               const float* __restrict__ pb,
               float* __restrict__ io)
{
    const int tid = threadIdx.x;
    const int lane = tid & 63;
    const int w = tid >> 6;
    const int l15 = lane & 15, lg = lane >> 4;
    const size_t rbase = (size_t)blockIdx.x * 64 + w * 16;

    const float* rp = io + (rbase + l15) * 128 + lg * 8;
    bf16x8 aH[4], aL[4];
    #pragma unroll
    for (int ks = 0; ks < 4; ++ks) {
        float4 a = *(const float4*)(rp + ks * 32);
        float4 c = *(const float4*)(rp + ks * 32 + 4);
        cvt8(a, c, aH[ks], aL[ks]);
    }

    f32x4 acc[8];
    #pragma unroll
    for (int i = 0; i < 8; ++i) acc[i] = (f32x4){0.f, 0.f, 0.f, 0.f};

    #pragma unroll
    for (int ks = 0; ks < 4; ++ks) {
        #pragma unroll
        for (int ct = 0; ct < 8; ++ct) {
            int ro = ((ks * 4 + lg) * 128 + ct * 16 + l15) * 8;
            bf16x8 bh = *(const bf16x8*)(pwsp + ro);
            bf16x8 bl = *(const bf16x8*)(pwsp + 16384 + ro);
            acc[ct] = MFMA16(aH[ks], bh, acc[ct], 0, 0, 0);
            acc[ct] = MFMA16(aH[ks], bl, acc[ct], 0, 0, 0);
            acc[ct] = MFMA16(aL[ks], bh, acc[ct], 0, 0, 0);
        }
    }

    #pragma unroll
    for (int ct = 0; ct < 8; ++ct) {
        float bias = pb[ct * 16 + l15];
        #pragma unroll
        for (int reg = 0; reg < 4; ++reg)
            io[(rbase + lg * 4 + reg) * 128 + ct * 16 + l15] = acc[ct][reg] + bias;
    }
}

// ---------------- round-4 fallback kernels (known-correct) ----------------
constexpr int QC_OFF = 0;
constexpr int KC_OFF = 8320;
constexpr int VC_OFF = 24960;
constexpr int P_OFF  = 41856;
constexpr int LDS_TOT = 50176;

__global__ __launch_bounds__(256, 2)
void attn_mfma(const float* __restrict__ x,
               const float* __restrict__ qkv_b,
               const float* __restrict__ bias_table,
               const unsigned short* __restrict__ wsp,
               float* __restrict__ out)
{
    __shared__ __attribute__((aligned(128))) char lds[LDS_TOT];
    const int tid = threadIdx.x;
    const int lane = tid & 63;
    const int w = tid >> 6;
    const int l15 = lane & 15, lg = lane >> 4;
    const int rowbase = 16 * w;
    const int b = blockIdx.x >> 2, h = blockIdx.x & 3;
    const float* __restrict__ xb = x + (size_t)b * 262144;
    const float* xrow0 = xb + ((size_t)(rowbase + l15) * 32) * 128 + lg * 8;

    bf16x8 aH[4], aL[4];
    bf16x8 kH[4], kL[4];
    int cur_na = -1, cur_nk = -1;

    auto loadfrags = [&](int n0, bf16x8 (&H)[4], bf16x8 (&L)[4]) {
        const float* p = xrow0 + (size_t)n0 * 128;
        #pragma unroll
        for (int ks = 0; ks < 4; ++ks) {
            float4 a = *(const float4*)(p + ks * 32);
            float4 c = *(const float4*)(p + ks * 32 + 4);
            cvt8(a, c, H[ks], L[ks]);
        }
    };

    auto mm_band = [&](const bf16x8 (&H)[4], const bf16x8 (&L)[4], int band,
                       f32x4& a0, f32x4& a1) {
        const unsigned short* wb = wsp + (size_t)band * 4096;
        #pragma unroll
        for (int ks = 0; ks < 4; ++ks) {
            int ro = ((ks * 4 + lg) * 32 + l15) * 8;
            bf16x8 b0h = *(const bf16x8*)(wb + ro);
            bf16x8 b0l = *(const bf16x8*)(wb + 49152 + ro);
            bf16x8 b1h = *(const bf16x8*)(wb + ro + 128);
            bf16x8 b1l = *(const bf16x8*)(wb + 49152 + ro + 128);
            a0 = MFMA16(H[ks], b0h, a0, 0, 0, 0);
            a0 = MFMA16(H[ks], b0l, a0, 0, 0, 0);
            a0 = MFMA16(L[ks], b0h, a0, 0, 0, 0);
            a1 = MFMA16(H[ks], b1h, a1, 0, 0, 0);
            a1 = MFMA16(H[ks], b1l, a1, 0, 0, 0);
            a1 = MFMA16(L[ks], b1h, a1, 0, 0, 0);
        }
    };

    auto store_rc = [&](char* base, f32x4 a0, f32x4 a1, float b0, float b1) {
        #pragma unroll
        for (int reg = 0; reg < 4; ++reg) {
            int s = rowbase + lg * 4 + reg;
            {
                float v = a0[reg] + b0;
                int i = l15;
                int off = (i >> 3) * 1040 + s * 16 + (i & 7) * 2;
                unsigned r = rne16(v);
                *(unsigned short*)(base + off) = (unsigned short)(r >> 16);
                *(unsigned short*)(base + 4160 + off) =
                    (unsigned short)(rne16(v - __uint_as_float(r)) >> 16);
            }
            {
                float v = a1[reg] + b1;
                int i = 16 + l15;
                int off = (i >> 3) * 1040 + s * 16 + (i & 7) * 2;
                unsigned r = rne16(v);
                *(unsigned short*)(base + off) = (unsigned short)(r >> 16);
                *(unsigned short*)(base + 4160 + off) =
                    (unsigned short)(rne16(v - __uint_as_float(r)) >> 16);
            }
        }
    };

    f32x4 accQK[4];
    #pragma unroll
    for (int tt = 0; tt < 4; ++tt) accQK[tt] = (f32x4){0.f, 0.f, 0.f, 0.f};

    int buf = 0;
    for (int ccc = 0; ccc < 32; ++ccc) {
        int remq = h * 1024 + 32 * ccc;
        int nq = remq / 384, j0q = remq - nq * 384, bandq = j0q >> 5;
        int remk = 4096 + h * 1024 + 32 * ccc;
        int nk = remk / 384, j0k = remk - nk * 384, bandk = j0k >> 5;
        if (nq != cur_na) { loadfrags(nq, aH, aL); cur_na = nq; }
        if (nk != cur_nk) { loadfrags(nk, kH, kL); cur_nk = nk; }

        f32x4 q0 = (f32x4){0.f,0.f,0.f,0.f}, q1 = (f32x4){0.f,0.f,0.f,0.f};
        mm_band(aH, aL, bandq, q0, q1);
        store_rc(lds + QC_OFF, q0, q1, qkv_b[j0q + l15], qkv_b[j0q + 16 + l15]);

        f32x4 k0 = (f32x4){0.f,0.f,0.f,0.f}, k1 = (f32x4){0.f,0.f,0.f,0.f};
        mm_band(kH, kL, bandk, k0, k1);
        store_rc(lds + KC_OFF + buf * 8320, k0, k1, qkv_b[j0k + l15], qkv_b[j0k + 16 + l15]);

        __syncthreads();

        const char* qc = lds + QC_OFF + lg * 1040 + (rowbase + l15) * 16;
        bf16x8 qah = *(const bf16x8*)qc;
        bf16x8 qal = *(const bf16x8*)(qc + 4160);
        #pragma unroll
        for (int tt = 0; tt < 4; ++tt) {
            const char* kc = lds + KC_OFF + buf * 8320 + lg * 1040 + (tt * 16 + l15) * 16;
            bf16x8 kbh = *(const bf16x8*)kc;
            bf16x8 kbl = *(const bf16x8*)(kc + 4160);
            accQK[tt] = MFMA16(qah, kbh, accQK[tt], 0, 0, 0);
            accQK[tt] = MFMA16(qah, kbl, accQK[tt], 0, 0, 0);
            accQK[tt] = MFMA16(qal, kbh, accQK[tt], 0, 0, 0);
        }
        buf ^= 1;
    }

    {
        const float scale = 0.17677669529663687f;
        #pragma unroll
        for (int reg = 0; reg < 4; ++reg) {
            int s = rowbase + lg * 4 + reg;
            int i1 = s >> 3, j1 = s & 7;
            float Lv[4];
            float m = -1e30f;
            #pragma unroll
            for (int tt = 0; tt < 4; ++tt) {
                int t = tt * 16 + l15;
                int i2 = t >> 3, j2 = t & 7;
                float L = accQK[tt][reg] * scale
                        + bias_table[((i1 - i2 + 7) * 15 + (j1 - j2 + 7)) * 4 + h];
                Lv[tt] = L;
                m = fmaxf(m, L);
            }
            m = fmaxf(m, __shfl_xor(m, 1));
            m = fmaxf(m, __shfl_xor(m, 2));
            m = fmaxf(m, __shfl_xor(m, 4));
            m = fmaxf(m, __shfl_xor(m, 8));
            float sum = 0.f;
            #pragma unroll
            for (int tt = 0; tt < 4; ++tt) { Lv[tt] = __expf(Lv[tt] - m); sum += Lv[tt]; }
            sum += __shfl_xor(sum, 1);
            sum += __shfl_xor(sum, 2);
            sum += __shfl_xor(sum, 4);
            sum += __shfl_xor(sum, 8);
            float inv = 1.f / sum;
            #pragma unroll
            for (int tt = 0; tt < 4; ++tt) {
                int t = tt * 16 + l15;
                int off = (t >> 3) * 1040 + s * 16 + (t & 7) * 2;
                *(unsigned short*)(lds + P_OFF + off) = (unsigned short)(rne16(Lv[tt] * inv) >> 16);
            }
        }
    }

    cur_na = -1;
    int bufv = 0;
    float* ob = out + (size_t)b * 262144;
    for (int ccc = 0; ccc < 32; ++ccc) {
        int remv = 8192 + h * 1024 + 32 * ccc;
        int nv = remv / 384, j0v = remv - nv * 384, bandv = j0v >> 5;
        if (nv != cur_na) { loadfrags(nv, aH, aL); cur_na = nv; }

        f32x4 v0 = (f32x4){0.f,0.f,0.f,0.f}, v1 = (f32x4){0.f,0.f,0.f,0.f};
        mm_band(aH, aL, bandv, v0, v1);
        {
            char* base = lds + VC_OFF + bufv * 8448;
            float b0 = qkv_b[j0v + l15], b1 = qkv_b[j0v + 16 + l15];
            #pragma unroll
            for (int reg = 0; reg < 4; ++reg) {
                int t = rowbase + lg * 4 + reg;
                {
                    float v = v0[reg] + b0;
                    int i = l15;
                    int off = (t >> 3) * 528 + i * 16 + (t & 7) * 2;
                    unsigned r = rne16(v);
                    *(unsigned short*)(base + off) = (unsigned short)(r >> 16);
                    *(unsigned short*)(base + 4224 + off) =
                        (unsigned short)(rne16(v - __uint_as_float(r)) >> 16);
                }
                {
                    float v = v1[reg] + b1;
                    int i = 16 + l15;
                    int off = (t >> 3) * 528 + i * 16 + (t & 7) * 2;
                    unsigned r = rne16(v);
                    *(unsigned short*)(base + off) = (unsigned short)(r >> 16);
                    *(unsigned short*)(base + 4224 + off) =
                        (unsigned short)(rne16(v - __uint_as_float(r)) >> 16);
                }
            }
        }
        __syncthreads();

        f32x4 o0 = (f32x4){0.f,0.f,0.f,0.f}, o1 = (f32x4){0.f,0.f,0.f,0.f};
        #pragma unroll
        for (int ks = 0; ks < 2; ++ks) {
            bf16x8 pf = *(const bf16x8*)(lds + P_OFF + (ks * 4 + lg) * 1040 + (rowbase + l15) * 16);
            const char* vb = lds + VC_OFF + bufv * 8448 + (ks * 4 + lg) * 528;
            bf16x8 v0h = *(const bf16x8*)(vb + l15 * 16);
            bf16x8 v0l = *(const bf16x8*)(vb + 4224 + l15 * 16);
            bf16x8 v1h = *(const bf16x8*)(vb + (16 + l15) * 16);
            bf16x8 v1l = *(const bf16x8*)(vb + 4224 + (16 + l15) * 16);
            o0 = MFMA16(pf, v0h, o0, 0, 0, 0);
            o0 = MFMA16(pf, v0l, o0, 0, 0, 0);
            o1 = MFMA16(pf, v1h, o1, 0, 0, 0);
            o1 = MFMA16(pf, v1l, o1, 0, 0, 0);
        }
        bufv ^= 1;

        #pragma unroll
        for (int reg = 0; reg < 4; ++reg) {
            int s = rowbase + lg * 4 + reg;
            {
                int d = 32 * ccc + l15;
                ob[(s * 32 + h * 8 + (d >> 7)) * 128 + (d & 127)] = o0[reg];
            }
            {
                int d = 32 * ccc + 16 + l15;
                ob[(s * 32 + h * 8 + (d >> 7)) * 128 + (d & 127)] = o1[reg];
            }
        }
    }
}

constexpr int LDS_B = 128 * 132 + 64 * 132;

__global__ __launch_bounds__(256, 1)
void proj_inplace(const float* __restrict__ pw,
                  const float* __restrict__ pb,
                  float* __restrict__ io)
{
    __shared__ float lds[LDS_B];
    float* pwt  = lds;
    float* rows = lds + 128 * 132;
    const int tid = threadIdx.x;

    for (int idx = tid; idx < 128 * 128; idx += 256) {
        const int c = idx >> 7, cp = idx & 127;
        pwt[cp * 132 + c] = pw[idx];
    }
    const int rb = tid >> 5;
    const int cg = tid & 31;
    const float4 pbv = *(const float4*)(pb + cg * 4);

    for (int it = 0; it < 8; ++it) {
        const size_t base = ((size_t)blockIdx.x * 8 + it) * 64;
        __syncthreads();
        for (int f = tid; f < 64 * 32; f += 256) {
            const int r = f >> 5, c4 = f & 31;
            *(float4*)(rows + r * 132 + c4 * 4) =
                *(const float4*)(io + (base + r) * 128 + c4 * 4);
        }
        __syncthreads();
        float acc[8][4] = {};
        #pragma unroll 2
        for (int cp = 0; cp < 128; ++cp) {
            const float4 wv = *(const float4*)(pwt + cp * 132 + cg * 4);
            #pragma unroll
            for (int rr = 0; rr < 8; ++rr) {
                const float xv = rows[(rb * 8 + rr) * 132 + cp];
                acc[rr][0] += xv * wv.x;
                acc[rr][1] += xv * wv.y;
                acc[rr][2] += xv * wv.z;
                acc[rr][3] += xv * wv.w;
            }
        }
        #pragma unroll
        for (int rr = 0; rr < 8; ++rr) {
            float4 o;
            o.x = acc[rr][0] + pbv.x;
            o.y = acc[rr][1] + pbv.y;
            o.z = acc[rr][2] + pbv.z;
            o.w = acc[rr][3] + pbv.w;
            *(float4*)(io + (base + rb * 8 + rr) * 128 + cg * 4) = o;
        }
    }
}

extern "C" void kernel_launch(void* const* d_in, const int* in_sizes, int n_in,
                              void* d_out, int out_size, void* d_ws, size_t ws_size,
                              hipStream_t stream)
{
    const float* x          = (const float*)d_in[0];
    const float* qkv_w      = (const float*)d_in[1];
    const float* qkv_b      = (const float*)d_in[2];
    const float* proj_w     = (const float*)d_in[3];
    const float* proj_b     = (const float*)d_in[4];
    const float* bias_table = (const float*)d_in[5];
    float* out = (float*)d_out;

    if (ws_size >= 262144 && d_ws != nullptr) {
        unsigned short* wsp = (unsigned short*)d_ws;
        unsigned short* pwsp = wsp + 98304;
        split_w<<<dim3(192), dim3(256), 0, stream>>>(qkv_w, wsp);
        split_pw<<<dim3(64), dim3(256), 0, stream>>>(proj_w, pwsp);
        attn_mfma5b<<<dim3(512), dim3(512), 0, stream>>>(x, qkv_b, bias_table, wsp, out);
        proj_mfma<<<dim3(4096), dim3(256), 0, stream>>>(pwsp, proj_b, out);
    } else if (ws_size >= 196608 && d_ws != nullptr) {
        unsigned short* wsp = (unsigned short*)d_ws;
        split_w<<<dim3(192), dim3(256), 0, stream>>>(qkv_w, wsp);
        attn_mfma<<<dim3(512), dim3(256), 0, stream>>>(x, qkv_b, bias_table, wsp, out);
        proj_inplace<<<dim3(512), dim3(256), 0, stream>>>(proj_w, proj_b, out);
    }
}